// Round 2
// baseline (349.196 us; speedup 1.0000x reference)
//
#include <hip/hip_runtime.h>
#include <hip/hip_bf16.h>
#include <stdint.h>

// Problem constants (from reference)
#define O_DIM   4096
#define I_DIM   2048
#define M_DENSE 8192
#define K_DENSE 4096
#define N_TOK   4096
#define K_ACT   2048

typedef __bf16 bf16x8 __attribute__((ext_vector_type(8)));
typedef float  f32x4  __attribute__((ext_vector_type(4)));

// round-to-nearest-even fp32 -> bf16 bits
__device__ __forceinline__ unsigned f2bf(float f) {
    unsigned u = __builtin_bit_cast(unsigned, f);
    return (u + 0x7FFFu + ((u >> 16) & 1u)) >> 16;
}

// async global->LDS, 16 bytes per lane; LDS dest = wave-uniform base + lane*16
__device__ __forceinline__ void load16(const unsigned short* g, unsigned short* l) {
    __builtin_amdgcn_global_load_lds(
        (__attribute__((address_space(1))) void*)(g),
        (__attribute__((address_space(3))) void*)(l),
        16, 0, 0);
}

// Zero only the INACTIVE dense output rows (rows not in indices[]).
// Active rows are fully overwritten by the GEMM epilogue.
__global__ void zero_inactive(const int* __restrict__ indices, float4* __restrict__ out4) {
    int row = blockIdx.y;
    __shared__ int active;
    if (threadIdx.x == 0) {
        int lo = 0, hi = O_DIM;
        while (lo < hi) { int mid = (lo + hi) >> 1; if (indices[mid] < row) lo = mid + 1; else hi = mid; }
        active = (lo < O_DIM && indices[lo] == row) ? 1 : 0;
    }
    __syncthreads();
    if (active) return;
    int col4 = blockIdx.x * 256 + threadIdx.x;           // N_TOK/4 = 1024 per row
    out4[(size_t)row * (N_TOK / 4) + col4] = float4{0.f, 0.f, 0.f, 0.f};
}

// A2[o][j] (bf16 bits, [O_DIM x K_ACT] row-major). Iterate over ACTIVE j:
// dense col c = idx[j]; value = weight[o,2g] if metadata[o,2g]==c&3 else
// weight[o,2g+1] if metadata[o,2g+1]==c&3 else 0, with g = c>>2.
// Coalesced 16B writes; metadata/weight gathers are monotonic in j (L1-friendly).
__global__ void decompress_w(const float* __restrict__ weight,
                             const int* __restrict__ metadata,
                             const int* __restrict__ idx,
                             uint4* __restrict__ A2) {
    int gid = blockIdx.x * blockDim.x + threadIdx.x;     // O_DIM * K_ACT/8 threads
    int o  = gid >> 8;                                   // 256 j-octets per row
    int j0 = (gid & 255) * 8;
    const int*   mrow = metadata + (size_t)o * I_DIM;
    const float* wrow = weight   + (size_t)o * I_DIM;
    int4 c0 = *(const int4*)(idx + j0);
    int4 c1 = *(const int4*)(idx + j0 + 4);
    int cs[8] = {c0.x, c0.y, c0.z, c0.w, c1.x, c1.y, c1.z, c1.w};
    unsigned r[8];
#pragma unroll
    for (int u = 0; u < 8; ++u) {
        int c = cs[u];
        int g2 = (c >> 2) * 2;
        int pos = c & 3;
        int2   mm = *(const int2*)(mrow + g2);
        float2 ww = *(const float2*)(wrow + g2);
        float v = (mm.x == pos) ? ww.x : ((mm.y == pos) ? ww.y : 0.0f);
        r[u] = f2bf(v);
    }
    uint4 packed;
    packed.x = r[0] | (r[1] << 16);
    packed.y = r[2] | (r[3] << 16);
    packed.z = r[4] | (r[5] << 16);
    packed.w = r[6] | (r[7] << 16);
    A2[gid] = packed;
}

// input fp32 [N_TOK x K_ACT] -> bf16 bits, same layout (this IS B^T: [n][k])
__global__ void cast_b(const float4* __restrict__ in, uint4* __restrict__ outb) {
    int gid = blockIdx.x * blockDim.x + threadIdx.x;     // N_TOK*K_ACT/8 threads
    float4 a = in[2 * gid], b = in[2 * gid + 1];
    uint4 u;
    u.x = f2bf(a.x) | (f2bf(a.y) << 16);
    u.y = f2bf(a.z) | (f2bf(a.w) << 16);
    u.z = f2bf(b.x) | (f2bf(b.y) << 16);
    u.w = f2bf(b.z) | (f2bf(b.w) << 16);
    outb[gid] = u;
}

// GEMM: C[o][t] = sum_j A2[o][j] * Bt[t][j]; rows scattered to out[indices[o]].
// M=4096, N=4096, K=2048. 128x128 tile, BK=32, 4 waves, 16x16x32 bf16 MFMA.
// LDS k-segment is XOR-swizzled by (row&3) to break the 4-way bank aliasing
// of 64B-stride ds_read_b128 (applied at staging source + read offset; both
// are loop-invariant pointer math).
__global__ void gemm_scatter(const unsigned short* __restrict__ A,
                             const unsigned short* __restrict__ Bt,
                             const int* __restrict__ indices,
                             float* __restrict__ out) {
    constexpr int N = N_TOK, K = K_ACT;
    constexpr int TM = 128, TN = 128, BK = 32;
    __shared__ alignas(16) unsigned short sA[TM * BK];
    __shared__ alignas(16) unsigned short sB[TN * BK];

    const int t    = threadIdx.x;       // 0..255
    const int wave = t >> 6;            // 0..3
    const int lane = t & 63;
    const int m0 = blockIdx.y * TM;
    const int n0 = blockIdx.x * TN;

    // staging: flat chunk f covers LDS elements [f*8, f*8+8) = (row=f>>2, slot=f&3).
    // Physical slot s holds global k-segment s ^ (row&3)  ->  source seg below.
    const int fa0 = t, fa1 = t + 256;
    const int r0 = fa0 >> 2, s0 = (fa0 & 3) ^ (r0 & 3);
    const int r1 = fa1 >> 2, s1 = (fa1 & 3) ^ (r1 & 3);
    const unsigned short* gA0 = A  + (size_t)(m0 + r0) * K + s0 * 8;
    const unsigned short* gA1 = A  + (size_t)(m0 + r1) * K + s1 * 8;
    const unsigned short* gB0 = Bt + (size_t)(n0 + r0) * K + s0 * 8;
    const unsigned short* gB1 = Bt + (size_t)(n0 + r1) * K + s1 * 8;

    unsigned short* lA0 = sA + wave * 512;
    unsigned short* lA1 = sA + 2048 + wave * 512;
    unsigned short* lB0 = sB + wave * 512;
    unsigned short* lB1 = sB + 2048 + wave * 512;

    const int wm   = (wave >> 1) * 64;  // wave's 64x64 quadrant
    const int wn   = (wave & 1) * 64;
    const int quad = lane >> 4;
    const int lr   = lane & 15;
    // read: want global k-segment `quad` of row r -> physical slot quad^(r&3);
    // all row bases (wm, mi*16, ni*16) are multiples of 4, so r&3 == lr&3.
    const int kq   = (quad ^ (lr & 3)) * 8;

    f32x4 acc[4][4] = {};

    for (int kk = 0; kk < K; kk += BK) {
        __syncthreads();   // previous compute done before overwriting LDS
        load16(gA0 + kk, lA0);
        load16(gA1 + kk, lA1);
        load16(gB0 + kk, lB0);
        load16(gB1 + kk, lB1);
        __syncthreads();   // drains vmcnt before barrier

        bf16x8 af[4], bf[4];
#pragma unroll
        for (int mi = 0; mi < 4; ++mi)
            af[mi] = *(const bf16x8*)(sA + (wm + mi * 16 + lr) * BK + kq);
#pragma unroll
        for (int ni = 0; ni < 4; ++ni)
            bf[ni] = *(const bf16x8*)(sB + (wn + ni * 16 + lr) * BK + kq);
#pragma unroll
        for (int mi = 0; mi < 4; ++mi)
#pragma unroll
            for (int ni = 0; ni < 4; ++ni)
                acc[mi][ni] = __builtin_amdgcn_mfma_f32_16x16x32_bf16(
                    af[mi], bf[ni], acc[mi][ni], 0, 0, 0);
    }

    // epilogue: D lane layout col=lane&15, row=quad*4+reg (m91-verified)
#pragma unroll
    for (int mi = 0; mi < 4; ++mi) {
#pragma unroll
        for (int r = 0; r < 4; ++r) {
            int gm = m0 + wm + mi * 16 + quad * 4 + r;
            int orow = indices[gm];
            float* op = out + (size_t)orow * N + n0 + wn + lr;
#pragma unroll
            for (int ni = 0; ni < 4; ++ni)
                op[ni * 16] = acc[mi][ni][r];
        }
    }
}

extern "C" void kernel_launch(void* const* d_in, const int* in_sizes, int n_in,
                              void* d_out, int out_size, void* d_ws, size_t ws_size,
                              hipStream_t stream) {
    const float* input    = (const float*)d_in[0];
    const int*   idx      = (const int*)d_in[1];
    const float* weight   = (const float*)d_in[2];
    const int*   indices  = (const int*)d_in[3];
    const int*   metadata = (const int*)d_in[4];
    float* out = (float*)d_out;

    // workspace layout: A2 (16 MB) | Bbt (16 MB)
    unsigned short* A2  = (unsigned short*)d_ws;
    unsigned short* Bbt = (unsigned short*)((char*)d_ws + (size_t)(16 << 20));

    zero_inactive<<<dim3(N_TOK / 1024, M_DENSE), 256, 0, stream>>>(indices, (float4*)out);
    decompress_w<<<(O_DIM * K_ACT / 8) / 256, 256, 0, stream>>>(
        weight, metadata, idx, (uint4*)A2);
    cast_b<<<(N_TOK * K_ACT / 8) / 256, 256, 0, stream>>>((const float4*)input, (uint4*)Bbt);

    dim3 grid(N_TOK / 128, O_DIM / 128);  // (32, 32)
    gemm_scatter<<<grid, 256, 0, stream>>>(A2, Bbt, indices, out);
}

// Round 3
// 296.277 us; speedup vs baseline: 1.1786x; 1.1786x over previous
//
#include <hip/hip_runtime.h>
#include <hip/hip_bf16.h>
#include <stdint.h>

// Problem constants (from reference)
#define O_DIM   4096
#define I_DIM   2048
#define M_DENSE 8192
#define K_DENSE 4096
#define N_TOK   4096
#define K_ACT   2048

typedef __bf16 bf16x8 __attribute__((ext_vector_type(8)));
typedef float  f32x4  __attribute__((ext_vector_type(4)));

// round-to-nearest-even fp32 -> bf16 bits
__device__ __forceinline__ unsigned f2bf(float f) {
    unsigned u = __builtin_bit_cast(unsigned, f);
    return (u + 0x7FFFu + ((u >> 16) & 1u)) >> 16;
}

// async global->LDS, 16 bytes per lane; LDS dest = wave-uniform base + lane*16
__device__ __forceinline__ void load16(const unsigned short* g, unsigned short* l) {
    __builtin_amdgcn_global_load_lds(
        (__attribute__((address_space(1))) void*)(g),
        (__attribute__((address_space(3))) void*)(l),
        16, 0, 0);
}

// Zero only the INACTIVE dense output rows. Inactive rows are exactly the
// gaps in the sorted `indices` list: block b zeroes rows in the open
// interval (indices[b-1], indices[b]). No binary search, coalesced stores.
__global__ void zero_inactive(const int* __restrict__ indices, float4* __restrict__ out4) {
    int b = blockIdx.x;                                  // 0 .. O_DIM
    int lo = (b == 0) ? -1 : indices[b - 1];             // broadcast load
    int hi = (b == O_DIM) ? M_DENSE : indices[b];
    for (int row = lo + 1; row < hi; ++row) {
        float4* dst = out4 + (size_t)row * (N_TOK / 4);
        for (int c = threadIdx.x; c < N_TOK / 4; c += 256)
            dst[c] = float4{0.f, 0.f, 0.f, 0.f};
    }
}

// A2[o][j] (bf16 bits, [O_DIM x K_ACT] row-major). One block per row o:
// stage metadata/weight row (16 KB) in LDS coalesced, then per-active-j
// gathers are LDS reads. value for j: c=idx[j], g=c>>2, pos=c&3;
// weight[o,2g+s] where metadata[o,2g+s]==pos, else 0.
__global__ __launch_bounds__(256) void decompress_w(const float* __restrict__ weight,
                                                    const int* __restrict__ metadata,
                                                    const int* __restrict__ idx,
                                                    uint4* __restrict__ A2) {
    __shared__ int   smeta[I_DIM];
    __shared__ float sw[I_DIM];
    int o = blockIdx.x;
    const int4*   mrow = (const int4*)(metadata + (size_t)o * I_DIM);
    const float4* wrow = (const float4*)(weight + (size_t)o * I_DIM);
#pragma unroll
    for (int it = 0; it < I_DIM / 4 / 256; ++it) {
        int i = it * 256 + threadIdx.x;
        *(int4*)(smeta + i * 4) = mrow[i];
        *(float4*)(sw + i * 4)  = wrow[i];
    }
    __syncthreads();
    int j0 = threadIdx.x * 8;                            // 256 threads * 8 = K_ACT
    int4 c0 = *(const int4*)(idx + j0);
    int4 c1 = *(const int4*)(idx + j0 + 4);
    int cs[8] = {c0.x, c0.y, c0.z, c0.w, c1.x, c1.y, c1.z, c1.w};
    unsigned r[8];
#pragma unroll
    for (int u = 0; u < 8; ++u) {
        int c = cs[u];
        int g2 = (c >> 2) * 2;
        int pos = c & 3;
        int m0v = smeta[g2], m1v = smeta[g2 + 1];
        float v = (m0v == pos) ? sw[g2] : ((m1v == pos) ? sw[g2 + 1] : 0.0f);
        r[u] = f2bf(v);
    }
    uint4 packed;
    packed.x = r[0] | (r[1] << 16);
    packed.y = r[2] | (r[3] << 16);
    packed.z = r[4] | (r[5] << 16);
    packed.w = r[6] | (r[7] << 16);
    A2[((size_t)o * K_ACT + j0) >> 3] = packed;
}

// input fp32 [N_TOK x K_ACT] -> bf16 bits, same layout (this IS B^T: [n][k])
__global__ void cast_b(const float4* __restrict__ in, uint4* __restrict__ outb) {
    int gid = blockIdx.x * blockDim.x + threadIdx.x;     // N_TOK*K_ACT/8 threads
    float4 a = in[2 * gid], b = in[2 * gid + 1];
    uint4 u;
    u.x = f2bf(a.x) | (f2bf(a.y) << 16);
    u.y = f2bf(a.z) | (f2bf(a.w) << 16);
    u.z = f2bf(b.x) | (f2bf(b.y) << 16);
    u.w = f2bf(b.z) | (f2bf(b.w) << 16);
    outb[gid] = u;
}

// GEMM: C[o][t] = sum_j A2[o][j] * Bt[t][j]; rows scattered to out[indices[o]].
// M=4096, N=4096, K=2048. 128x128 tile, BK=32, 4 waves, 16x16x32 bf16 MFMA.
// (No LDS swizzle: R2 showed SQ_LDS_BANK_CONFLICT is structural for wave64
// ds_read_b128 — swizzling left it bit-identical at 2^23.)
__global__ void gemm_scatter(const unsigned short* __restrict__ A,
                             const unsigned short* __restrict__ Bt,
                             const int* __restrict__ indices,
                             float* __restrict__ out) {
    constexpr int N = N_TOK, K = K_ACT;
    constexpr int TM = 128, TN = 128, BK = 32;
    __shared__ alignas(16) unsigned short sA[TM * BK];
    __shared__ alignas(16) unsigned short sB[TN * BK];

    const int t    = threadIdx.x;       // 0..255
    const int wave = t >> 6;            // 0..3
    const int lane = t & 63;
    const int m0 = blockIdx.y * TM;
    const int n0 = blockIdx.x * TN;

    // staging: flat chunk f = q*256+t covers LDS elements [f*8, f*8+8)
    // = row (f>>2) of tile, k-segment (f&3)*8.
    const int fa0 = t, fa1 = t + 256;
    const unsigned short* gA0 = A  + (size_t)(m0 + (fa0 >> 2)) * K + (fa0 & 3) * 8;
    const unsigned short* gA1 = A  + (size_t)(m0 + (fa1 >> 2)) * K + (fa1 & 3) * 8;
    const unsigned short* gB0 = Bt + (size_t)(n0 + (fa0 >> 2)) * K + (fa0 & 3) * 8;
    const unsigned short* gB1 = Bt + (size_t)(n0 + (fa1 >> 2)) * K + (fa1 & 3) * 8;

    unsigned short* lA0 = sA + wave * 512;
    unsigned short* lA1 = sA + 2048 + wave * 512;
    unsigned short* lB0 = sB + wave * 512;
    unsigned short* lB1 = sB + 2048 + wave * 512;

    const int wm   = (wave >> 1) * 64;  // wave's 64x64 quadrant
    const int wn   = (wave & 1) * 64;
    const int quad = lane >> 4;
    const int lr   = lane & 15;
    const int kq   = quad * 8;

    f32x4 acc[4][4] = {};

    for (int kk = 0; kk < K; kk += BK) {
        __syncthreads();   // previous compute done before overwriting LDS
        load16(gA0 + kk, lA0);
        load16(gA1 + kk, lA1);
        load16(gB0 + kk, lB0);
        load16(gB1 + kk, lB1);
        __syncthreads();   // drains vmcnt before barrier

        bf16x8 af[4], bf[4];
#pragma unroll
        for (int mi = 0; mi < 4; ++mi)
            af[mi] = *(const bf16x8*)(sA + (wm + mi * 16 + lr) * BK + kq);
#pragma unroll
        for (int ni = 0; ni < 4; ++ni)
            bf[ni] = *(const bf16x8*)(sB + (wn + ni * 16 + lr) * BK + kq);
#pragma unroll
        for (int mi = 0; mi < 4; ++mi)
#pragma unroll
            for (int ni = 0; ni < 4; ++ni)
                acc[mi][ni] = __builtin_amdgcn_mfma_f32_16x16x32_bf16(
                    af[mi], bf[ni], acc[mi][ni], 0, 0, 0);
    }

    // epilogue: D lane layout col=lane&15, row=quad*4+reg (m91-verified)
#pragma unroll
    for (int mi = 0; mi < 4; ++mi) {
#pragma unroll
        for (int r = 0; r < 4; ++r) {
            int gm = m0 + wm + mi * 16 + quad * 4 + r;
            int orow = indices[gm];
            float* op = out + (size_t)orow * N + n0 + wn + lr;
#pragma unroll
            for (int ni = 0; ni < 4; ++ni)
                op[ni * 16] = acc[mi][ni][r];
        }
    }
}

extern "C" void kernel_launch(void* const* d_in, const int* in_sizes, int n_in,
                              void* d_out, int out_size, void* d_ws, size_t ws_size,
                              hipStream_t stream) {
    const float* input    = (const float*)d_in[0];
    const int*   idx      = (const int*)d_in[1];
    const float* weight   = (const float*)d_in[2];
    const int*   indices  = (const int*)d_in[3];
    const int*   metadata = (const int*)d_in[4];
    float* out = (float*)d_out;

    // workspace layout: A2 (16 MB) | Bbt (16 MB)
    unsigned short* A2  = (unsigned short*)d_ws;
    unsigned short* Bbt = (unsigned short*)((char*)d_ws + (size_t)(16 << 20));

    zero_inactive<<<O_DIM + 1, 256, 0, stream>>>(indices, (float4*)out);
    decompress_w<<<O_DIM, 256, 0, stream>>>(weight, metadata, idx, (uint4*)A2);
    cast_b<<<(N_TOK * K_ACT / 8) / 256, 256, 0, stream>>>((const float4*)input, (uint4*)Bbt);

    dim3 grid(N_TOK / 128, O_DIM / 128);  // (32, 32)
    gemm_scatter<<<grid, 256, 0, stream>>>(A2, Bbt, indices, out);
}

// Round 4
// 291.201 us; speedup vs baseline: 1.1992x; 1.0174x over previous
//
#include <hip/hip_runtime.h>
#include <hip/hip_bf16.h>
#include <stdint.h>

// Problem constants (from reference)
#define O_DIM   4096
#define I_DIM   2048
#define M_DENSE 8192
#define K_DENSE 4096
#define N_TOK   4096
#define K_ACT   2048

typedef __bf16 bf16x8 __attribute__((ext_vector_type(8)));
typedef float  f32x4  __attribute__((ext_vector_type(4)));

// round-to-nearest-even fp32 -> bf16 bits
__device__ __forceinline__ unsigned f2bf(float f) {
    unsigned u = __builtin_bit_cast(unsigned, f);
    return (u + 0x7FFFu + ((u >> 16) & 1u)) >> 16;
}

// async global->LDS, 16 bytes per lane; LDS dest = wave-uniform base + lane*16
__device__ __forceinline__ void load16(const unsigned short* g, unsigned short* l) {
    __builtin_amdgcn_global_load_lds(
        (__attribute__((address_space(1))) void*)(g),
        (__attribute__((address_space(3))) void*)(l),
        16, 0, 0);
}

// Merged prep: blocks [0,O_DIM) decompress weights, blocks [O_DIM, O_DIM+4096) cast input.
//
// decompress: A2[o][j] (bf16 bits, [O_DIM x K_ACT] row-major). One block per
// row o: stage metadata/weight row (16 KB) in LDS coalesced, then per-active-j
// gathers are LDS reads. value for j: c=idx[j], g=c>>2, pos=c&3;
// weight[o,2g+s] where metadata[o,2g+s]==pos, else 0.
// cast: input fp32 [N_TOK x K_ACT] -> bf16 bits, same layout (B^T: [n][k]).
__global__ __launch_bounds__(256) void prep(const float* __restrict__ weight,
                                            const int* __restrict__ metadata,
                                            const int* __restrict__ idx,
                                            const float* __restrict__ input,
                                            uint4* __restrict__ A2,
                                            uint4* __restrict__ Bbt) {
    if (blockIdx.x >= O_DIM) {
        // ---- cast branch ----
        int gid = (blockIdx.x - O_DIM) * 256 + threadIdx.x;  // 4096 blocks
        const float4* in = (const float4*)input;
        float4 a = in[2 * gid], b = in[2 * gid + 1];
        uint4 u;
        u.x = f2bf(a.x) | (f2bf(a.y) << 16);
        u.y = f2bf(a.z) | (f2bf(a.w) << 16);
        u.z = f2bf(b.x) | (f2bf(b.y) << 16);
        u.w = f2bf(b.z) | (f2bf(b.w) << 16);
        Bbt[gid] = u;
        return;
    }
    // ---- decompress branch ----
    __shared__ int   smeta[I_DIM];
    __shared__ float sw[I_DIM];
    int o = blockIdx.x;
    const int4*   mrow = (const int4*)(metadata + (size_t)o * I_DIM);
    const float4* wrow = (const float4*)(weight + (size_t)o * I_DIM);
#pragma unroll
    for (int it = 0; it < I_DIM / 4 / 256; ++it) {
        int i = it * 256 + threadIdx.x;
        *(int4*)(smeta + i * 4) = mrow[i];
        *(float4*)(sw + i * 4)  = wrow[i];
    }
    __syncthreads();
    int j0 = threadIdx.x * 8;                            // 256 threads * 8 = K_ACT
    int4 c0 = *(const int4*)(idx + j0);
    int4 c1 = *(const int4*)(idx + j0 + 4);
    int cs[8] = {c0.x, c0.y, c0.z, c0.w, c1.x, c1.y, c1.z, c1.w};
    unsigned r[8];
#pragma unroll
    for (int u = 0; u < 8; ++u) {
        int c = cs[u];
        int g2 = (c >> 2) * 2;
        int pos = c & 3;
        int m0v = smeta[g2], m1v = smeta[g2 + 1];
        float v = (m0v == pos) ? sw[g2] : ((m1v == pos) ? sw[g2 + 1] : 0.0f);
        r[u] = f2bf(v);
    }
    uint4 packed;
    packed.x = r[0] | (r[1] << 16);
    packed.y = r[2] | (r[3] << 16);
    packed.z = r[4] | (r[5] << 16);
    packed.w = r[6] | (r[7] << 16);
    A2[((size_t)o * K_ACT + j0) >> 3] = packed;
}

// GEMM: C[o][t] = sum_j A2[o][j] * Bt[t][j]; rows scattered to out[indices[o]].
// M=4096, N=4096, K=2048. 128x128 tile, BK=32, 4 waves, 16x16x32 bf16 MFMA.
// Prologue also zeroes this block's share of the INACTIVE dense output rows:
// block (bx,by) owns dense rows [by*256, by*256+256) x cols [bx*128,+128).
// (No LDS swizzle: SQ_LDS_BANK_CONFLICT is structural for wave64 ds_read_b128
// — R2's swizzle left it bit-identical at 2^23.)
__global__ __launch_bounds__(256, 4) void gemm_scatter(
        const unsigned short* __restrict__ A,
        const unsigned short* __restrict__ Bt,
        const int* __restrict__ indices,
        float* __restrict__ out) {
    constexpr int N = N_TOK, K = K_ACT;
    constexpr int TM = 128, TN = 128, BK = 32;
    __shared__ alignas(16) unsigned short sA[TM * BK];
    __shared__ alignas(16) unsigned short sB[TN * BK];
    __shared__ int s_list[256];
    __shared__ int s_cnt;

    const int t    = threadIdx.x;       // 0..255
    const int wave = t >> 6;            // 0..3
    const int lane = t & 63;
    const int m0 = blockIdx.y * TM;
    const int n0 = blockIdx.x * TN;

    // ---- zero this block's inactive-row slice (overlaps first staging) ----
    {
        if (t == 0) s_cnt = 0;
        int r = blockIdx.y * 256 + t;                    // dense row
        int lo = 0, hi = O_DIM;
        while (lo < hi) { int mid = (lo + hi) >> 1; if (indices[mid] < r) lo = mid + 1; else hi = mid; }
        bool inactive = !(lo < O_DIM && indices[lo] == r);
        __syncthreads();
        if (inactive) { int p = atomicAdd(&s_cnt, 1); s_list[p] = r; }
        __syncthreads();
        int nin = s_cnt;
        float4 z4 = {0.f, 0.f, 0.f, 0.f};
        for (int task = t; task < nin * 32; task += 256) {
            int row = s_list[task >> 5];
            int c4  = task & 31;                         // 32 float4 = 128 cols
            *(float4*)(out + (size_t)row * N + n0 + c4 * 4) = z4;
        }
    }

    // staging: flat chunk f = q*256+t covers LDS elements [f*8, f*8+8)
    // = row (f>>2) of tile, k-segment (f&3)*8.
    const int fa0 = t, fa1 = t + 256;
    const unsigned short* gA0 = A  + (size_t)(m0 + (fa0 >> 2)) * K + (fa0 & 3) * 8;
    const unsigned short* gA1 = A  + (size_t)(m0 + (fa1 >> 2)) * K + (fa1 & 3) * 8;
    const unsigned short* gB0 = Bt + (size_t)(n0 + (fa0 >> 2)) * K + (fa0 & 3) * 8;
    const unsigned short* gB1 = Bt + (size_t)(n0 + (fa1 >> 2)) * K + (fa1 & 3) * 8;

    unsigned short* lA0 = sA + wave * 512;
    unsigned short* lA1 = sA + 2048 + wave * 512;
    unsigned short* lB0 = sB + wave * 512;
    unsigned short* lB1 = sB + 2048 + wave * 512;

    const int wm   = (wave >> 1) * 64;  // wave's 64x64 quadrant
    const int wn   = (wave & 1) * 64;
    const int quad = lane >> 4;
    const int lr   = lane & 15;
    const int kq   = quad * 8;

    f32x4 acc[4][4] = {};

    for (int kk = 0; kk < K; kk += BK) {
        __syncthreads();   // previous compute done before overwriting LDS
        load16(gA0 + kk, lA0);
        load16(gA1 + kk, lA1);
        load16(gB0 + kk, lB0);
        load16(gB1 + kk, lB1);
        __syncthreads();   // drains vmcnt before barrier

        bf16x8 af[4], bf[4];
#pragma unroll
        for (int mi = 0; mi < 4; ++mi)
            af[mi] = *(const bf16x8*)(sA + (wm + mi * 16 + lr) * BK + kq);
#pragma unroll
        for (int ni = 0; ni < 4; ++ni)
            bf[ni] = *(const bf16x8*)(sB + (wn + ni * 16 + lr) * BK + kq);
#pragma unroll
        for (int mi = 0; mi < 4; ++mi)
#pragma unroll
            for (int ni = 0; ni < 4; ++ni)
                acc[mi][ni] = __builtin_amdgcn_mfma_f32_16x16x32_bf16(
                    af[mi], bf[ni], acc[mi][ni], 0, 0, 0);
    }

    // epilogue: D lane layout col=lane&15, row=quad*4+reg (m91-verified)
#pragma unroll
    for (int mi = 0; mi < 4; ++mi) {
#pragma unroll
        for (int r = 0; r < 4; ++r) {
            int gm = m0 + wm + mi * 16 + quad * 4 + r;
            int orow = indices[gm];
            float* op = out + (size_t)orow * N + n0 + wn + lr;
#pragma unroll
            for (int ni = 0; ni < 4; ++ni)
                op[ni * 16] = acc[mi][ni][r];
        }
    }
}

extern "C" void kernel_launch(void* const* d_in, const int* in_sizes, int n_in,
                              void* d_out, int out_size, void* d_ws, size_t ws_size,
                              hipStream_t stream) {
    const float* input    = (const float*)d_in[0];
    const int*   idx      = (const int*)d_in[1];
    const float* weight   = (const float*)d_in[2];
    const int*   indices  = (const int*)d_in[3];
    const int*   metadata = (const int*)d_in[4];
    float* out = (float*)d_out;

    // workspace layout: A2 (16 MB) | Bbt (16 MB)
    unsigned short* A2  = (unsigned short*)d_ws;
    unsigned short* Bbt = (unsigned short*)((char*)d_ws + (size_t)(16 << 20));

    // prep: 4096 decompress blocks + 4096 cast blocks
    prep<<<O_DIM + (N_TOK * K_ACT / 8) / 256, 256, 0, stream>>>(
        weight, metadata, idx, input, (uint4*)A2, (uint4*)Bbt);

    dim3 grid(N_TOK / 128, O_DIM / 128);  // (32, 32)
    gemm_scatter<<<grid, 256, 0, stream>>>(A2, Bbt, indices, out);
}